// Round 4
// baseline (431.913 us; speedup 1.0000x reference)
//
#include <hip/hip_runtime.h>
#include <hip/hip_bf16.h>
#include <math.h>

#define DM 768
#define ED 1536
#define NS 16
#define DTR 48
#define BATCH 16
#define LQ 197
#define NTOK (BATCH*LQ)      // 3152
#define NWTOK (64*49)        // 3136
#define TTOK (2*NTOK+NWTOK)  // 9440
#define TPAD 9456
#define MPAD 3200

typedef __attribute__((ext_vector_type(8))) short short8;
typedef __attribute__((ext_vector_type(4))) float f32x4;
typedef __attribute__((ext_vector_type(4))) short s16x4;

__device__ __forceinline__ unsigned short f2bf(float f) {
  unsigned int u = __float_as_uint(f);
  unsigned int r = (u + 0x7FFFu + ((u >> 16) & 1u)) >> 16;
  return (unsigned short)r;
}
__device__ __forceinline__ float bf2f(unsigned short u) {
  return __uint_as_float(((unsigned int)u) << 16);
}
__device__ __forceinline__ float silu_f(float x) {
  return x / (1.f + __expf(-x));
}

// ---------------- batched f32 -> bf16 convert of all weights/inputs ----------------
__global__ void k_cvtall(const float* __restrict__ x, const float* __restrict__ Win,
                         const float* __restrict__ xp0, const float* __restrict__ xp1,
                         const float* __restrict__ xp2, const float* __restrict__ Wout,
                         unsigned short* __restrict__ XB, unsigned short* __restrict__ WINB,
                         unsigned short* __restrict__ XPB, unsigned short* __restrict__ WOUTB)
{
  int i = blockIdx.x * 256 + threadIdx.x;
  const int n0 = NTOK * DM;
  const int n1 = n0 + 2 * ED * DM;
  const int n2 = n1 + 80 * ED;
  const int n3 = n2 + 80 * ED;
  const int n4 = n3 + 80 * ED;
  const int n5 = n4 + DM * ED;
  if (i < n0) XB[i] = f2bf(x[i]);
  else if (i < n1) WINB[i - n0] = f2bf(Win[i - n0]);
  else if (i < n2) XPB[i - n1] = f2bf(xp0[i - n1]);
  else if (i < n3) XPB[(i - n2) + 80 * ED] = f2bf(xp1[i - n2]);
  else if (i < n4) XPB[(i - n3) + 160 * ED] = f2bf(xp2[i - n3]);
  else if (i < n5) WOUTB[i - n4] = f2bf(Wout[i - n4]);
}

// ---------------- LDS-staged bf16 MFMA GEMM: C[M][N] = A[M][K] * B[N][K]^T ----------------
__global__ __launch_bounds__(256) void k_gemm_lds(
    const unsigned short* __restrict__ A, const unsigned short* __restrict__ B,
    float* __restrict__ C, float* __restrict__ C2,
    int M, int N, int K, int mode)
{
  __shared__ unsigned short As[128 * 64];
  __shared__ unsigned short Bs[128 * 64];
  int tid = threadIdx.x;
  int wave = tid >> 6, lane = tid & 63;
  int m0 = blockIdx.x * 128, n0 = blockIdx.y * 128;
  int wm = (wave >> 1) * 64, wn = (wave & 1) * 64;
  int lr = lane & 15, lk = lane >> 4;

  f32x4 acc[4][4];
#pragma unroll
  for (int i = 0; i < 4; ++i)
#pragma unroll
    for (int j = 0; j < 4; ++j) acc[i][j] = (f32x4){0.f, 0.f, 0.f, 0.f};

  const unsigned short* Ab = A + (size_t)m0 * K;
  const unsigned short* Bb = B + (size_t)n0 * K;

  for (int kk = 0; kk < K; kk += 64) {
    __syncthreads();
#pragma unroll
    for (int j = 0; j < 4; ++j) {
      int c = j * 256 + wave * 64 + lane;     // chunk index 0..1023 (16B chunks)
      int row = c >> 3, kc = c & 7;
      __builtin_amdgcn_global_load_lds(
        (const __attribute__((address_space(1))) unsigned int*)(Ab + (size_t)row * K + kk + kc * 8),
        (__attribute__((address_space(3))) unsigned int*)(As + (size_t)(j * 256 + wave * 64) * 8),
        16, 0, 0);
      __builtin_amdgcn_global_load_lds(
        (const __attribute__((address_space(1))) unsigned int*)(Bb + (size_t)row * K + kk + kc * 8),
        (__attribute__((address_space(3))) unsigned int*)(Bs + (size_t)(j * 256 + wave * 64) * 8),
        16, 0, 0);
    }
    __syncthreads();
#pragma unroll
    for (int ks = 0; ks < 2; ++ks) {
      short8 av[4], bv[4];
#pragma unroll
      for (int i = 0; i < 4; ++i) {
        av[i] = *(const short8*)(As + (wm + i * 16 + lr) * 64 + ks * 32 + lk * 8);
        bv[i] = *(const short8*)(Bs + (wn + i * 16 + lr) * 64 + ks * 32 + lk * 8);
      }
#pragma unroll
      for (int i = 0; i < 4; ++i)
#pragma unroll
        for (int jj = 0; jj < 4; ++jj)
          acc[i][jj] = __builtin_amdgcn_mfma_f32_16x16x32_bf16(av[i], bv[jj], acc[i][jj], 0, 0, 0);
    }
  }

  int cn = lane & 15, rb = (lane >> 4) * 4;
#pragma unroll
  for (int i = 0; i < 4; ++i)
#pragma unroll
    for (int jj = 0; jj < 4; ++jj)
#pragma unroll
      for (int r = 0; r < 4; ++r) {
        int row = m0 + wm + i * 16 + rb + r;
        int col = n0 + wn + jj * 16 + cn;
        if (row < M && col < N) {
          float v = acc[i][jj][r];
          if (mode == 1) {
            if (col < ED) C[(size_t)row * ED + col] = v;
            else          C2[(size_t)row * ED + (col - ED)] = silu_f(v);
          } else {
            C[(size_t)row * N + col] = v;
          }
        }
      }
}

// ---------------- causal depthwise conv: thread = one channel, register history ----------------
// grid (12, 16, 2), block 128. Reads each XIN row exactly once per branch.
__global__ __launch_bounds__(128) void k_conv(
    const float* __restrict__ xin,
    const float* __restrict__ cw0, const float* __restrict__ cb0,
    const float* __restrict__ cw1, const float* __restrict__ cb1,
    unsigned short* __restrict__ UB)
{
  int e = blockIdx.x * 128 + threadIdx.x;
  int b = blockIdx.y, pz = blockIdx.z;
  const float* cw = pz ? cw1 : cw0;
  const float* cb = pz ? cb1 : cb0;
  float w0 = cw[e * 4], w1 = cw[e * 4 + 1], w2 = cw[e * 4 + 2], w3 = cw[e * 4 + 3];
  float bias = cb[e];
  const float* xb = xin + (size_t)b * LQ * ED + e;
  unsigned short* ob = UB + (size_t)(pz * NTOK + b * LQ) * ED + e;
  float x1 = 0.f, x2 = 0.f, x3 = 0.f;
  float xc = xb[0];   // perm(0) == 0 for both branches
  for (int t = 0; t < LQ; ++t) {
    float xn = 0.f;
    if (t + 1 < LQ) {
      int tt = t + 1;
      int tok = (pz == 0) ? tt : (tt < 196 ? (tt % 14) * 14 + tt / 14 : 196);
      xn = xb[(size_t)tok * ED];
    }
    float s = bias + xc * w3 + x1 * w2 + x2 * w1 + x3 * w0;
    ob[(size_t)t * ED] = f2bf(silu_f(s));
    x3 = x2; x2 = x1; x1 = xc; xc = xn;
  }
}

// ---------------- window scale+bias+silu -> UB rows 6304.. ----------------
__global__ __launch_bounds__(256) void k_win(
    const float* __restrict__ xin, const float* __restrict__ w2,
    const float* __restrict__ b2, unsigned short* __restrict__ UB)
{
  int j = blockIdx.x;  // 0..48
  int s = blockIdx.y;  // 0..63  (= q*16+b)
  int q = s >> 4, b = s & 15;
  int hh = j / 7 + 7 * (q >> 1);
  int ww = j % 7 + 7 * (q & 1);
  int tok = hh * 14 + ww;
  size_t ibase = ((size_t)(b * LQ + tok)) * ED;
  size_t obase = ((size_t)(2 * NTOK + s * 49 + j)) * ED;
  for (int e = threadIdx.x; e < ED; e += 256)
    UB[obase + e] = f2bf(silu_f(xin[ibase + e] * w2[e] + b2[e]));
}

// ---------------- dbc GEMM: DBC[tok][80] = UB[tok][1536] @ XPB(branch)[80][1536]^T ----------------
__global__ __launch_bounds__(256) void k_dbc(
    const unsigned short* __restrict__ A, const unsigned short* __restrict__ XPB,
    float* __restrict__ C)
{
  __shared__ float red[4][16][80];
  int tid = threadIdx.x;
  int wave = tid >> 6, lane = tid & 63;
  int m0 = blockIdx.x * 16;
  int branch = (m0 >= 2 * NTOK) ? 2 : (m0 >= NTOK ? 1 : 0);
  const unsigned short* B = XPB + (size_t)branch * 80 * ED;
  int lr = lane & 15;
  int kof = wave * 384 + (lane >> 4) * 8;

  f32x4 acc[5];
#pragma unroll
  for (int j = 0; j < 5; ++j) acc[j] = (f32x4){0.f, 0.f, 0.f, 0.f};

  const unsigned short* Ap = A + (size_t)(m0 + lr) * ED + kof;
  const unsigned short* Bp = B + (size_t)lr * ED + kof;
#pragma unroll
  for (int kk = 0; kk < 384; kk += 32) {
    short8 av = *(const short8*)(Ap + kk);
#pragma unroll
    for (int j = 0; j < 5; ++j) {
      short8 bv = *(const short8*)(Bp + (size_t)j * 16 * ED + kk);
      acc[j] = __builtin_amdgcn_mfma_f32_16x16x32_bf16(av, bv, acc[j], 0, 0, 0);
    }
  }
  int cn = lane & 15, rb = (lane >> 4) * 4;
#pragma unroll
  for (int j = 0; j < 5; ++j)
#pragma unroll
    for (int r = 0; r < 4; ++r)
      red[wave][rb + r][j * 16 + cn] = acc[j][r];
  __syncthreads();
  for (int i = tid; i < 16 * 80; i += 256) {
    int r = i / 80, c = i % 80;
    C[(size_t)(m0 + r) * 80 + c] = red[0][r][c] + red[1][r][c] + red[2][r][c] + red[3][r][c];
  }
}

// ---------------- delta = softplus(dbc[:, :48] @ dt_w^T + dt_b) -> DELTA [tok][e] ----------------
__global__ __launch_bounds__(256) void k_delta(
    const float* __restrict__ dbc, const float* __restrict__ dtw,
    const float* __restrict__ dtb, float* __restrict__ DELTA)
{
  __shared__ float sd[16][DTR];
  int tbase = blockIdx.y * 16;
  int e = blockIdx.x * 256 + threadIdx.x;
  for (int i = threadIdx.x; i < 16 * DTR; i += 256)
    sd[i / DTR][i % DTR] = dbc[(size_t)(tbase + i / DTR) * 80 + (i % DTR)];
  __syncthreads();
  float w[DTR];
#pragma unroll
  for (int k = 0; k < DTR; ++k) w[k] = dtw[e * DTR + k];
  float bias = dtb[e];
  for (int tt = 0; tt < 16; ++tt) {
    float s = bias;
#pragma unroll
    for (int k = 0; k < DTR; ++k) s += sd[tt][k] * w[k];
    float dv = (s > 20.f) ? s : log1pf(__expf(s));
    DELTA[(size_t)(tbase + tt) * ED + e] = dv;
  }
}

// ---------------- SSM scan: thread = (seq, e), 16 states in-thread, no shfl ----------------
// grid (24, 96), block 64 (one wave). B/C addresses wave-uniform. u/d prefetched 4 steps ahead.
__global__ __launch_bounds__(64) void k_scan(
    const unsigned short* __restrict__ UB, const float* __restrict__ DELTA,
    const float* __restrict__ DBC, const float* __restrict__ alog,
    float* __restrict__ Y0, float* __restrict__ Y1, float* __restrict__ Y2)
{
  int e = blockIdx.x * 64 + threadIdx.x;
  int seq = blockIdx.y;                    // 0..95
  int L, tokbase, yrow;
  float* Y;
  if (seq < 16)      { L = LQ; tokbase = seq * LQ;                   Y = Y0; yrow = seq * LQ; }
  else if (seq < 32) { L = LQ; tokbase = NTOK + (seq - 16) * LQ;     Y = Y1; yrow = (seq - 16) * LQ; }
  else               { L = 49; tokbase = 2 * NTOK + (seq - 32) * 49; Y = Y2; yrow = (seq - 32) * 49; }

  float A2[16], h[16];
#pragma unroll
  for (int n = 0; n < 16; ++n) {
    A2[n] = -__expf(alog[e * NS + n]) * 1.44269504f;   // pre-scale for exp2
    h[n] = 0.f;
  }

  const unsigned short* up = UB + (size_t)tokbase * ED + e;
  const float* dp = DELTA + (size_t)tokbase * ED + e;
  const float* bc = DBC + (size_t)tokbase * 80 + 48;
  float* yp = Y + (size_t)yrow * ED + e;

  int nb = (L + 3) >> 2;
  float uc[4], dc[4];
#pragma unroll
  for (int k = 0; k < 4; ++k) {
    uc[k] = bf2f(up[(size_t)k * ED]);
    dc[k] = dp[(size_t)k * ED];
  }

  for (int tb = 0; tb < nb; ++tb) {
    float un[4], dn[4];
    if (tb + 1 < nb) {
      int baset = (tb + 1) * 4;
#pragma unroll
      for (int k = 0; k < 4; ++k) {
        un[k] = bf2f(up[(size_t)(baset + k) * ED]);
        dn[k] = dp[(size_t)(baset + k) * ED];
      }
    } else {
#pragma unroll
      for (int k = 0; k < 4; ++k) { un[k] = 0.f; dn[k] = 0.f; }
    }
#pragma unroll
    for (int k = 0; k < 4; ++k) {
      int t = tb * 4 + k;
      const f32x4* bcp = (const f32x4*)(bc + (size_t)t * 80);
      f32x4 Bv0 = bcp[0], Bv1 = bcp[1], Bv2 = bcp[2], Bv3 = bcp[3];
      f32x4 Cv0 = bcp[4], Cv1 = bcp[5], Cv2 = bcp[6], Cv3 = bcp[7];
      float d = dc[k];
      float du = d * uc[k];
      float y0 = 0.f, y1 = 0.f, y2 = 0.f, y3 = 0.f;
#pragma unroll
      for (int n = 0; n < 4; ++n) {
        h[n]      = exp2f(d * A2[n])      * h[n]      + du * Bv0[n];
        h[n + 4]  = exp2f(d * A2[n + 4])  * h[n + 4]  + du * Bv1[n];
        h[n + 8]  = exp2f(d * A2[n + 8])  * h[n + 8]  + du * Bv2[n];
        h[n + 12] = exp2f(d * A2[n + 12]) * h[n + 12] + du * Bv3[n];
        y0 += Cv0[n] * h[n];
        y1 += Cv1[n] * h[n + 4];
        y2 += Cv2[n] * h[n + 8];
        y3 += Cv3[n] * h[n + 12];
      }
      if (t < L) yp[(size_t)t * ED] = (y0 + y1) + (y2 + y3);
    }
#pragma unroll
    for (int k = 0; k < 4; ++k) { uc[k] = un[k]; dc[k] = dn[k]; }
  }
}

// ---------------- combine 3 branch outputs + ct1 + *silu(z) -> bf16 PREB ----------------
__global__ void k_combine(const float* __restrict__ Y0, const float* __restrict__ Y1,
                          const float* __restrict__ Y2, const float* __restrict__ ZS,
                          unsigned short* __restrict__ PREB)
{
  int i = blockIdx.x * 256 + threadIdx.x;   // over NTOK * 384
  int tok = i / 384, e4 = (i - tok * 384) * 4;
  int b = tok / LQ, p = tok - b * LQ;

  int t0 = (p == 0) ? 196 : p - 1;
  f32x4 v0 = *(const f32x4*)(Y0 + ((size_t)(b * LQ + t0)) * ED + e4);

  int t1;
  if (p == 0) t1 = 196;
  else { int pp = p - 1; t1 = (pp % 14) * 14 + pp / 14; }
  f32x4 v1 = *(const f32x4*)(Y1 + ((size_t)(b * LQ + t1)) * ED + e4);

  f32x4 v2;
  if (p == 196) {
    v2 = *(const f32x4*)(Y1 + ((size_t)(b * LQ + 196)) * ED + e4);
  } else {
    int hh = p / 14, ww = p - hh * 14;
    int q = ((hh >= 7) ? 2 : 0) + ((ww >= 7) ? 1 : 0);
    int j = (hh % 7) * 7 + (ww % 7);
    v2 = *(const f32x4*)(Y2 + ((size_t)((q * 16 + b) * 49 + j)) * ED + e4);
  }
  f32x4 z = *(const f32x4*)(ZS + (size_t)tok * ED + e4);
  s16x4 r;
#pragma unroll
  for (int k = 0; k < 4; ++k) r[k] = (short)f2bf((v0[k] + v1[k] + v2[k]) * z[k]);
  *(s16x4*)(PREB + (size_t)tok * ED + e4) = r;
}

extern "C" void kernel_launch(void* const* d_in, const int* in_sizes, int n_in,
                              void* d_out, int out_size, void* d_ws, size_t ws_size,
                              hipStream_t stream)
{
  const float* x    = (const float*)d_in[0];
  const float* Win  = (const float*)d_in[1];
  const float* c0w  = (const float*)d_in[2];
  const float* c0b  = (const float*)d_in[3];
  const float* c1w  = (const float*)d_in[4];
  const float* c1b  = (const float*)d_in[5];
  const float* c2w  = (const float*)d_in[6];
  const float* c2b  = (const float*)d_in[7];
  const float* xp0  = (const float*)d_in[8];
  const float* xp1  = (const float*)d_in[9];
  const float* xp2  = (const float*)d_in[10];
  const float* dtw  = (const float*)d_in[11];
  const float* dtb  = (const float*)d_in[12];
  const float* alog = (const float*)d_in[13];
  const float* Wout = (const float*)d_in[15];
  float* out = (float*)d_out;

  char* base = (char*)d_ws;
  size_t off = 0;
  auto alloc = [&](size_t bytes) -> char* {
    char* r = base + off;
    off = (off + bytes + 255) & ~(size_t)255;
    return r;
  };

  float* ZS    = (float*)alloc((size_t)NTOK * ED * 4);
  float* Y0    = (float*)alloc((size_t)NTOK * ED * 4);
  float* Y1    = (float*)alloc((size_t)NTOK * ED * 4);
  float* XIN   = (float*)alloc((size_t)NTOK * ED * 4);   // Y2 aliases after XIN is dead
  unsigned short* UB    = (unsigned short*)alloc((size_t)TPAD * ED * 2);
  float* DELTA = (float*)alloc((size_t)TPAD * ED * 4);
  float* DBC   = (float*)alloc((size_t)TPAD * 80 * 4);
  unsigned short* PREB  = (unsigned short*)alloc((size_t)MPAD * ED * 2);
  unsigned short* WOUTB = (unsigned short*)alloc((size_t)DM * ED * 2);
  unsigned short* XPB   = (unsigned short*)alloc((size_t)3 * 80 * ED * 2);

  // aliases: XB + WINB live inside Y0 until gemm1 done; Y2 = XIN (dead after conv/win).
  unsigned short* XB   = (unsigned short*)Y0;                                 // MPAD x DM
  unsigned short* WINB = (unsigned short*)((char*)Y0 + (size_t)MPAD * DM * 2); // 3072 x DM
  float* Y2 = XIN;

  // convert all fp32 operands to bf16 in one launch
  {
    int ntot = NTOK * DM + 2 * ED * DM + 3 * 80 * ED + DM * ED;
    k_cvtall<<<(ntot + 255) / 256, 256, 0, stream>>>(x, Win, xp0, xp1, xp2, Wout,
                                                     XB, WINB, XPB, WOUTB);
  }

  // xz = x @ W_in^T  -> XIN (first ED cols), ZS = silu(z)
  k_gemm_lds<<<dim3(25, 24), 256, 0, stream>>>(XB, WINB, XIN, ZS, NTOK, 2 * ED, DM, 1);

  hipMemsetAsync(DBC, 0, (size_t)TPAD * 80 * 4, stream);  // covers scan-tail padding rows

  // u for all three branches -> UB [9440][1536] bf16
  k_conv<<<dim3(12, BATCH, 2), 128, 0, stream>>>(XIN, c0w, c0b, c1w, c1b, UB);
  k_win<<<dim3(49, 64), 256, 0, stream>>>(XIN, c2w, c2b, UB);

  // dbc for all branches (per-token xproj selection)
  k_dbc<<<TTOK / 16, 256, 0, stream>>>(UB, XPB, DBC);

  // delta for all branches
  k_delta<<<dim3(6, TTOK / 16), 256, 0, stream>>>(DBC, dtw, dtb, DELTA);

  // batched scan: 96 sequences x 1536 channels, 16 states per thread
  k_scan<<<dim3(24, 96), 64, 0, stream>>>(UB, DELTA, DBC, alog, Y0, Y1, Y2);

  // combine + output GEMM
  k_combine<<<(NTOK * 384 + 255) / 256, 256, 0, stream>>>(Y0, Y1, Y2, ZS, PREB);
  k_gemm_lds<<<dim3(25, 6), 256, 0, stream>>>(PREB, WOUTB, out, nullptr, NTOK, DM, ED, 0);
}

// Round 5
// 329.661 us; speedup vs baseline: 1.3102x; 1.3102x over previous
//
#include <hip/hip_runtime.h>
#include <hip/hip_bf16.h>
#include <math.h>

#define DM 768
#define ED 1536
#define NS 16
#define DTR 48
#define BATCH 16
#define LQ 197
#define NTOK (BATCH*LQ)      // 3152
#define NWTOK (64*49)        // 3136
#define TTOK (2*NTOK+NWTOK)  // 9440
#define TPAD 9456
#define MPAD 3200

typedef __attribute__((ext_vector_type(8))) short short8;
typedef __attribute__((ext_vector_type(4))) float f32x4;
typedef __attribute__((ext_vector_type(4))) short s16x4;

__device__ __forceinline__ unsigned short f2bf(float f) {
  unsigned int u = __float_as_uint(f);
  unsigned int r = (u + 0x7FFFu + ((u >> 16) & 1u)) >> 16;
  return (unsigned short)r;
}
__device__ __forceinline__ float bf2f(unsigned short u) {
  return __uint_as_float(((unsigned int)u) << 16);
}
__device__ __forceinline__ float silu_f(float x) {
  return x / (1.f + __expf(-x));
}

// ---------------- batched f32 -> bf16 convert of all weights/inputs ----------------
__global__ void k_cvtall(const float* __restrict__ x, const float* __restrict__ Win,
                         const float* __restrict__ xp0, const float* __restrict__ xp1,
                         const float* __restrict__ xp2, const float* __restrict__ Wout,
                         unsigned short* __restrict__ XB, unsigned short* __restrict__ WINB,
                         unsigned short* __restrict__ XPB, unsigned short* __restrict__ WOUTB)
{
  int i = blockIdx.x * 256 + threadIdx.x;
  const int n0 = NTOK * DM;
  const int n1 = n0 + 2 * ED * DM;
  const int n2 = n1 + 80 * ED;
  const int n3 = n2 + 80 * ED;
  const int n4 = n3 + 80 * ED;
  const int n5 = n4 + DM * ED;
  if (i < n0) XB[i] = f2bf(x[i]);
  else if (i < n1) WINB[i - n0] = f2bf(Win[i - n0]);
  else if (i < n2) XPB[i - n1] = f2bf(xp0[i - n1]);
  else if (i < n3) XPB[(i - n2) + 80 * ED] = f2bf(xp1[i - n2]);
  else if (i < n4) XPB[(i - n3) + 160 * ED] = f2bf(xp2[i - n3]);
  else if (i < n5) WOUTB[i - n4] = f2bf(Wout[i - n4]);
}

// ---------------- LDS-staged bf16 MFMA GEMM: C[M][N] = A[M][K] * B[N][K]^T ----------------
__global__ __launch_bounds__(256) void k_gemm_lds(
    const unsigned short* __restrict__ A, const unsigned short* __restrict__ B,
    float* __restrict__ C, float* __restrict__ C2,
    int M, int N, int K, int mode)
{
  __shared__ unsigned short As[128 * 64];
  __shared__ unsigned short Bs[128 * 64];
  int tid = threadIdx.x;
  int wave = tid >> 6, lane = tid & 63;
  int m0 = blockIdx.x * 128, n0 = blockIdx.y * 128;
  int wm = (wave >> 1) * 64, wn = (wave & 1) * 64;
  int lr = lane & 15, lk = lane >> 4;

  f32x4 acc[4][4];
#pragma unroll
  for (int i = 0; i < 4; ++i)
#pragma unroll
    for (int j = 0; j < 4; ++j) acc[i][j] = (f32x4){0.f, 0.f, 0.f, 0.f};

  const unsigned short* Ab = A + (size_t)m0 * K;
  const unsigned short* Bb = B + (size_t)n0 * K;

  for (int kk = 0; kk < K; kk += 64) {
    __syncthreads();
#pragma unroll
    for (int j = 0; j < 4; ++j) {
      int c = j * 256 + wave * 64 + lane;     // chunk index 0..1023 (16B chunks)
      int row = c >> 3, kc = c & 7;
      __builtin_amdgcn_global_load_lds(
        (const __attribute__((address_space(1))) unsigned int*)(Ab + (size_t)row * K + kk + kc * 8),
        (__attribute__((address_space(3))) unsigned int*)(As + (size_t)(j * 256 + wave * 64) * 8),
        16, 0, 0);
      __builtin_amdgcn_global_load_lds(
        (const __attribute__((address_space(1))) unsigned int*)(Bb + (size_t)row * K + kk + kc * 8),
        (__attribute__((address_space(3))) unsigned int*)(Bs + (size_t)(j * 256 + wave * 64) * 8),
        16, 0, 0);
    }
    __syncthreads();
#pragma unroll
    for (int ks = 0; ks < 2; ++ks) {
      short8 av[4], bv[4];
#pragma unroll
      for (int i = 0; i < 4; ++i) {
        av[i] = *(const short8*)(As + (wm + i * 16 + lr) * 64 + ks * 32 + lk * 8);
        bv[i] = *(const short8*)(Bs + (wn + i * 16 + lr) * 64 + ks * 32 + lk * 8);
      }
#pragma unroll
      for (int i = 0; i < 4; ++i)
#pragma unroll
        for (int jj = 0; jj < 4; ++jj)
          acc[i][jj] = __builtin_amdgcn_mfma_f32_16x16x32_bf16(av[i], bv[jj], acc[i][jj], 0, 0, 0);
    }
  }

  int cn = lane & 15, rb = (lane >> 4) * 4;
#pragma unroll
  for (int i = 0; i < 4; ++i)
#pragma unroll
    for (int jj = 0; jj < 4; ++jj)
#pragma unroll
      for (int r = 0; r < 4; ++r) {
        int row = m0 + wm + i * 16 + rb + r;
        int col = n0 + wn + jj * 16 + cn;
        if (row < M && col < N) {
          float v = acc[i][jj][r];
          if (mode == 1) {
            if (col < ED) C[(size_t)row * ED + col] = v;
            else          C2[(size_t)row * ED + (col - ED)] = silu_f(v);
          } else {
            C[(size_t)row * N + col] = v;
          }
        }
      }
}

// ---------------- causal depthwise conv (k=4) + bias + silu -> UB bf16 [tok][e] ----------------
// grid (96, 16, 2): 16-channel slice x batch x branch; LDS-tiled, XIN read once per branch.
__global__ __launch_bounds__(256) void k_conv(
    const float* __restrict__ xin,
    const float* __restrict__ cw0, const float* __restrict__ cb0,
    const float* __restrict__ cw1, const float* __restrict__ cb1,
    unsigned short* __restrict__ UB)
{
  __shared__ float xs[LQ][17];
  int eb = blockIdx.x, b = blockIdx.y, pz = blockIdx.z;
  const float* cw = pz ? cw1 : cw0;
  const float* cb = pz ? cb1 : cb0;
  int e0 = eb * 16;
  for (int i = threadIdx.x; i < LQ * 16; i += 256) {
    int tt = i >> 4, le = i & 15;
    int tok = (pz == 0) ? tt : (tt < 196 ? (tt % 14) * 14 + tt / 14 : 196);
    xs[tt][le] = xin[((size_t)(b * LQ + tok)) * ED + e0 + le];
  }
  __syncthreads();
  int le = threadIdx.x & 15, tq = threadIdx.x >> 4;
  int e = e0 + le;
  float w0 = cw[e * 4], w1 = cw[e * 4 + 1], w2 = cw[e * 4 + 2], w3 = cw[e * 4 + 3];
  float bias = cb[e];
  unsigned short* ob = UB + (size_t)(pz * NTOK + b * LQ) * ED + e;
  for (int t = tq; t < LQ; t += 16) {
    float s = bias + xs[t][le] * w3;
    if (t >= 1) s += xs[t - 1][le] * w2;
    if (t >= 2) s += xs[t - 2][le] * w1;
    if (t >= 3) s += xs[t - 3][le] * w0;
    ob[(size_t)t * ED] = f2bf(silu_f(s));
  }
}

// ---------------- window scale+bias+silu -> UB rows 6304.. ----------------
__global__ __launch_bounds__(256) void k_win(
    const float* __restrict__ xin, const float* __restrict__ w2,
    const float* __restrict__ b2, unsigned short* __restrict__ UB)
{
  int j = blockIdx.x;  // 0..48
  int s = blockIdx.y;  // 0..63  (= q*16+b)
  int q = s >> 4, b = s & 15;
  int hh = j / 7 + 7 * (q >> 1);
  int ww = j % 7 + 7 * (q & 1);
  int tok = hh * 14 + ww;
  size_t ibase = ((size_t)(b * LQ + tok)) * ED;
  size_t obase = ((size_t)(2 * NTOK + s * 49 + j)) * ED;
  for (int e = threadIdx.x; e < ED; e += 256)
    UB[obase + e] = f2bf(silu_f(xin[ibase + e] * w2[e] + b2[e]));
}

// ---------------- dbc GEMM: DBC[tok][80] = UB[tok][1536] @ XPB(branch)[80][1536]^T ----------------
__global__ __launch_bounds__(256) void k_dbc(
    const unsigned short* __restrict__ A, const unsigned short* __restrict__ XPB,
    float* __restrict__ C)
{
  __shared__ float red[4][16][80];
  int tid = threadIdx.x;
  int wave = tid >> 6, lane = tid & 63;
  int m0 = blockIdx.x * 16;
  int branch = (m0 >= 2 * NTOK) ? 2 : (m0 >= NTOK ? 1 : 0);
  const unsigned short* B = XPB + (size_t)branch * 80 * ED;
  int lr = lane & 15;
  int kof = wave * 384 + (lane >> 4) * 8;

  f32x4 acc[5];
#pragma unroll
  for (int j = 0; j < 5; ++j) acc[j] = (f32x4){0.f, 0.f, 0.f, 0.f};

  const unsigned short* Ap = A + (size_t)(m0 + lr) * ED + kof;
  const unsigned short* Bp = B + (size_t)lr * ED + kof;
#pragma unroll
  for (int kk = 0; kk < 384; kk += 32) {
    short8 av = *(const short8*)(Ap + kk);
#pragma unroll
    for (int j = 0; j < 5; ++j) {
      short8 bv = *(const short8*)(Bp + (size_t)j * 16 * ED + kk);
      acc[j] = __builtin_amdgcn_mfma_f32_16x16x32_bf16(av, bv, acc[j], 0, 0, 0);
    }
  }
  int cn = lane & 15, rb = (lane >> 4) * 4;
#pragma unroll
  for (int j = 0; j < 5; ++j)
#pragma unroll
    for (int r = 0; r < 4; ++r)
      red[wave][rb + r][j * 16 + cn] = acc[j][r];
  __syncthreads();
  for (int i = tid; i < 16 * 80; i += 256) {
    int r = i / 80, c = i % 80;
    C[(size_t)(m0 + r) * 80 + c] = red[0][r][c] + red[1][r][c] + red[2][r][c] + red[3][r][c];
  }
}

// ---------------- delta = softplus(dbc[:, :48] @ dt_w^T + dt_b) -> DELB bf16 [tok][e] ----------------
__global__ __launch_bounds__(256) void k_delta(
    const float* __restrict__ dbc, const float* __restrict__ dtw,
    const float* __restrict__ dtb, unsigned short* __restrict__ DELB)
{
  __shared__ float sd[16][DTR];
  int tbase = blockIdx.y * 16;
  int e = blockIdx.x * 256 + threadIdx.x;
  for (int i = threadIdx.x; i < 16 * DTR; i += 256)
    sd[i / DTR][i % DTR] = dbc[(size_t)(tbase + i / DTR) * 80 + (i % DTR)];
  __syncthreads();
  float w[DTR];
#pragma unroll
  for (int k = 0; k < DTR; ++k) w[k] = dtw[e * DTR + k];
  float bias = dtb[e];
  for (int tt = 0; tt < 16; ++tt) {
    float s = bias;
#pragma unroll
    for (int k = 0; k < DTR; ++k) s += sd[tt][k] * w[k];
    float dv = (s > 20.f) ? s : log1pf(__expf(s));
    DELB[(size_t)(tbase + tt) * ED + e] = f2bf(dv);
  }
}

// ---------------- SSM scan: 4 lanes x 4 states per (seq,e); ping-pong double-buffered ----------------
#define LOADBLK(tb, uu, dd, Bb, Cb)                                    \
  {                                                                    \
    int t0_ = (tb) * 4;                                                \
    _Pragma("unroll")                                                  \
    for (int k_ = 0; k_ < 4; ++k_) {                                   \
      uu[k_] = bf2f(up[(size_t)(t0_ + k_) * ED]);                      \
      dd[k_] = bf2f(dp[(size_t)(t0_ + k_) * ED]);                      \
      Bb[k_] = *(const f32x4*)(bp + (size_t)(t0_ + k_) * 80);          \
      Cb[k_] = *(const f32x4*)(bp + (size_t)(t0_ + k_) * 80 + 16);     \
    }                                                                  \
  }

#define COMPUTEBLK(tb, uu, dd, Bb, Cb)                                 \
  {                                                                    \
    _Pragma("unroll")                                                  \
    for (int k_ = 0; k_ < 4; ++k_) {                                   \
      int t_ = (tb) * 4 + k_;                                          \
      float d_ = dd[k_];                                               \
      float du_ = d_ * uu[k_];                                         \
      float y_ = 0.f;                                                  \
      _Pragma("unroll")                                                \
      for (int n_ = 0; n_ < 4; ++n_) {                                 \
        h[n_] = exp2f(d_ * A2[n_]) * h[n_] + du_ * Bb[k_][n_];         \
        y_ += Cb[k_][n_] * h[n_];                                      \
      }                                                                \
      y_ += __shfl_xor(y_, 1);                                         \
      y_ += __shfl_xor(y_, 2);                                         \
      if (lq == 0 && t_ < L) yp[(size_t)t_ * ED] = y_;                 \
    }                                                                  \
  }

__global__ __launch_bounds__(256) void k_scan(
    const unsigned short* __restrict__ UB, const unsigned short* __restrict__ DELB,
    const float* __restrict__ DBC, const float* __restrict__ alog,
    float* __restrict__ Y0, float* __restrict__ Y1, float* __restrict__ Y2)
{
  int g = blockIdx.x * 64 + (threadIdx.x >> 2);
  int lq = threadIdx.x & 3;
  int seq = g / ED;          // 0..95 (uniform per block: ED % 64 == 0)
  int e = g - seq * ED;
  int n0 = lq * 4;

  int L, tokbase, yrow;
  float* Y;
  if (seq < 16)      { L = LQ; tokbase = seq * LQ;                   Y = Y0; yrow = seq * LQ; }
  else if (seq < 32) { L = LQ; tokbase = NTOK + (seq - 16) * LQ;     Y = Y1; yrow = (seq - 16) * LQ; }
  else               { L = 49; tokbase = 2 * NTOK + (seq - 32) * 49; Y = Y2; yrow = (seq - 32) * 49; }

  float A2[4], h[4];
#pragma unroll
  for (int n = 0; n < 4; ++n) {
    A2[n] = -__expf(alog[e * NS + n0 + n]) * 1.44269504f;   // pre-scaled for exp2
    h[n] = 0.f;
  }

  const unsigned short* up = UB + (size_t)tokbase * ED + e;
  const unsigned short* dp = DELB + (size_t)tokbase * ED + e;
  const float* bp = DBC + (size_t)tokbase * 80 + 48 + n0;
  float* yp = Y + (size_t)yrow * ED + e;

  int nb = (L + 3) >> 2;   // 50 or 13

  float uA[4], dA_[4], uB_[4], dB_[4];
  f32x4 BA[4], CA[4], BB_[4], CB_[4];

  LOADBLK(0, uA, dA_, BA, CA);
  int tb2 = 0;
  for (; tb2 + 1 < nb; tb2 += 2) {
    LOADBLK(tb2 + 1, uB_, dB_, BB_, CB_);
    COMPUTEBLK(tb2, uA, dA_, BA, CA);
    if (tb2 + 2 < nb) LOADBLK(tb2 + 2, uA, dA_, BA, CA);
    COMPUTEBLK(tb2 + 1, uB_, dB_, BB_, CB_);
  }
  if (tb2 < nb) COMPUTEBLK(tb2, uA, dA_, BA, CA);
}

// ---------------- combine 3 branch outputs + ct1 + *silu(z) -> bf16 PREB ----------------
__global__ void k_combine(const float* __restrict__ Y0, const float* __restrict__ Y1,
                          const float* __restrict__ Y2, const float* __restrict__ ZS,
                          unsigned short* __restrict__ PREB)
{
  int i = blockIdx.x * 256 + threadIdx.x;   // over NTOK * 384
  int tok = i / 384, e4 = (i - tok * 384) * 4;
  int b = tok / LQ, p = tok - b * LQ;

  int t0 = (p == 0) ? 196 : p - 1;
  f32x4 v0 = *(const f32x4*)(Y0 + ((size_t)(b * LQ + t0)) * ED + e4);

  int t1;
  if (p == 0) t1 = 196;
  else { int pp = p - 1; t1 = (pp % 14) * 14 + pp / 14; }
  f32x4 v1 = *(const f32x4*)(Y1 + ((size_t)(b * LQ + t1)) * ED + e4);

  f32x4 v2;
  if (p == 196) {
    v2 = *(const f32x4*)(Y1 + ((size_t)(b * LQ + 196)) * ED + e4);
  } else {
    int hh = p / 14, ww = p - hh * 14;
    int q = ((hh >= 7) ? 2 : 0) + ((ww >= 7) ? 1 : 0);
    int j = (hh % 7) * 7 + (ww % 7);
    v2 = *(const f32x4*)(Y2 + ((size_t)((q * 16 + b) * 49 + j)) * ED + e4);
  }
  f32x4 z = *(const f32x4*)(ZS + (size_t)tok * ED + e4);
  s16x4 r;
#pragma unroll
  for (int k = 0; k < 4; ++k) r[k] = (short)f2bf((v0[k] + v1[k] + v2[k]) * z[k]);
  *(s16x4*)(PREB + (size_t)tok * ED + e4) = r;
}

extern "C" void kernel_launch(void* const* d_in, const int* in_sizes, int n_in,
                              void* d_out, int out_size, void* d_ws, size_t ws_size,
                              hipStream_t stream)
{
  const float* x    = (const float*)d_in[0];
  const float* Win  = (const float*)d_in[1];
  const float* c0w  = (const float*)d_in[2];
  const float* c0b  = (const float*)d_in[3];
  const float* c1w  = (const float*)d_in[4];
  const float* c1b  = (const float*)d_in[5];
  const float* c2w  = (const float*)d_in[6];
  const float* c2b  = (const float*)d_in[7];
  const float* xp0  = (const float*)d_in[8];
  const float* xp1  = (const float*)d_in[9];
  const float* xp2  = (const float*)d_in[10];
  const float* dtw  = (const float*)d_in[11];
  const float* dtb  = (const float*)d_in[12];
  const float* alog = (const float*)d_in[13];
  const float* Wout = (const float*)d_in[15];
  float* out = (float*)d_out;

  char* base = (char*)d_ws;
  size_t off = 0;
  auto alloc = [&](size_t bytes) -> char* {
    char* r = base + off;
    off = (off + bytes + 255) & ~(size_t)255;
    return r;
  };

  float* ZS    = (float*)alloc((size_t)NTOK * ED * 4);
  float* Y0    = (float*)alloc((size_t)NTOK * ED * 4);
  float* Y1    = (float*)alloc((size_t)NTOK * ED * 4);
  float* XIN   = (float*)alloc((size_t)NTOK * ED * 4);   // Y2 aliases after XIN is dead
  unsigned short* UB    = (unsigned short*)alloc((size_t)TPAD * ED * 2);
  unsigned short* DELB  = (unsigned short*)alloc((size_t)TPAD * ED * 2);
  float* DBC   = (float*)alloc((size_t)TPAD * 80 * 4);
  unsigned short* PREB  = (unsigned short*)alloc((size_t)MPAD * ED * 2);
  unsigned short* WOUTB = (unsigned short*)alloc((size_t)DM * ED * 2);
  unsigned short* XPB   = (unsigned short*)alloc((size_t)3 * 80 * ED * 2);

  // aliases: XB + WINB live inside Y0 until gemm1 done; Y2 = XIN (dead after conv/win).
  unsigned short* XB   = (unsigned short*)Y0;                                 // MPAD x DM
  unsigned short* WINB = (unsigned short*)((char*)Y0 + (size_t)MPAD * DM * 2); // 3072 x DM
  float* Y2 = XIN;

  // convert all fp32 operands to bf16 in one launch
  {
    int ntot = NTOK * DM + 2 * ED * DM + 3 * 80 * ED + DM * ED;
    k_cvtall<<<(ntot + 255) / 256, 256, 0, stream>>>(x, Win, xp0, xp1, xp2, Wout,
                                                     XB, WINB, XPB, WOUTB);
  }

  // xz = x @ W_in^T  -> XIN (first ED cols), ZS = silu(z)
  k_gemm_lds<<<dim3(25, 24), 256, 0, stream>>>(XB, WINB, XIN, ZS, NTOK, 2 * ED, DM, 1);

  // u for all three branches -> UB [9440][1536] bf16
  k_conv<<<dim3(96, BATCH, 2), 256, 0, stream>>>(XIN, c0w, c0b, c1w, c1b, UB);
  k_win<<<dim3(49, 64), 256, 0, stream>>>(XIN, c2w, c2b, UB);

  // dbc for all branches (per-token xproj selection)
  k_dbc<<<TTOK / 16, 256, 0, stream>>>(UB, XPB, DBC);

  // delta for all branches (bf16 output)
  k_delta<<<dim3(6, TTOK / 16), 256, 0, stream>>>(DBC, dtw, dtb, DELB);

  // batched scan: 96 sequences x 1536 channels, 4 lanes x 4 states, double-buffered
  k_scan<<<2304, 256, 0, stream>>>(UB, DELB, DBC, alog, Y0, Y1, Y2);

  // combine + output GEMM
  k_combine<<<(NTOK * 384 + 255) / 256, 256, 0, stream>>>(Y0, Y1, Y2, ZS, PREB);
  k_gemm_lds<<<dim3(25, 6), 256, 0, stream>>>(PREB, WOUTB, out, nullptr, NTOK, DM, ED, 0);
}